// Round 9
// baseline (127.694 us; speedup 1.0000x reference)
//
#include <hip/hip_runtime.h>

// ChebyshevAdditiveAngularMargin — two-phase, HBM-bound.
//   cosine = clip(outputs, -1+1e-7, 1-1e-7)
//   phi    = clenshaw(cosine, coeffs); phi = cosine > TH ? phi : cosine - MM
//   out    = targets one-hot (values exactly 1.0f):
//            out[r][c] = 30 * (c == label[r] ? phi : cosine)
//
// Ladder: R1 162 -> R4 one-shot 4xfloat4 145 -> R7 +NT streaming pair 115.
// R8 depth-8 forced batch: null -> MLP not binding; fabric carries 768MB
// (512 HBM NT + 256 L3 targets) ~= 6.7 TB/s aggregate = ceiling. R9: remove
// targets from the hot loop. k1 scans targets (cached, L3-resident) into
// labels[8192] in d_ws; k2 is a pure 2-stream NT kernel (read outputs,
// write dst) + uniform scalar label per block.

namespace {

typedef float f32x4 __attribute__((ext_vector_type(4)));

constexpr float kClipLo = -0.9999999f;   // -1 + 1e-7 rounded to f32
constexpr float kClipHi =  0.9999999f;   //  1 - 1e-7 rounded to f32
constexpr float kTH     = -0.98006657784124163f;  // cos(pi - 0.2)
constexpr float kMM     =  0.039733866159012243f; // sin(pi - 0.2) * 0.2
constexpr float kSCALE  = 30.0f;
constexpr int   kDegree = 30;            // 31 coefficients
constexpr int   kC      = 8192;          // columns per row
constexpr int   kPerThread = 4;          // float4s per thread per array (k2)

__device__ __forceinline__ float clenshaw_phi(float x, const float* __restrict__ coeffs) {
    // b_k = c_k + 2x*b_{k+1} - b_{k+2}, k = DEGREE..0;  f(x) = b_0 - x*b_1
    const float x2 = 2.0f * x;
    float b1 = 0.0f, b2 = 0.0f;
#pragma unroll
    for (int k = kDegree; k >= 0; --k) {
        float b = coeffs[k] + x2 * b1 - b2;
        b2 = b1;
        b1 = b;
    }
    return b1 - b2 * x;
}

// ---- k1: targets (one-hot) -> labels[row]. Cached loads keep targets
// L3-resident; exactly one write per row -> labels fully rewritten per call.
__global__ __launch_bounds__(256) void scan_labels_kernel(
    const f32x4* __restrict__ targets4,
    int*         __restrict__ labels,
    int n4) {
    const int tid    = blockIdx.x * blockDim.x + threadIdx.x;
    const int stride = gridDim.x * blockDim.x;
    for (int i = tid; i < n4; i += stride) {
        const f32x4 t = targets4[i];
        if (t[0] != 0.0f || t[1] != 0.0f || t[2] != 0.0f || t[3] != 0.0f) {
            const int base = i * 4;
#pragma unroll
            for (int j = 0; j < 4; ++j) {
                if (t[j] != 0.0f) {
                    const int idx = base + j;
                    labels[idx >> 13] = idx & (kC - 1);   // kC = 8192 = 2^13
                }
            }
        }
    }
}

// ---- k2: pure 2-stream NT kernel. Each block covers 1024 consecutive
// float4 = half a row; row (= blockIdx.x>>1) and label are wave-uniform.
__global__ __launch_bounds__(256) void cheb_aam_kernel(
    const f32x4* __restrict__ outputs4,
    const int*   __restrict__ labels,
    const float* __restrict__ coeffs,
    f32x4*       __restrict__ dst4) {
    const int base   = blockIdx.x * (256 * kPerThread) + threadIdx.x;
    const int row    = blockIdx.x >> 1;            // 2048 float4 per row
    const int hotIdx = row * kC + labels[row];     // global float index of the 1

    f32x4 o[kPerThread];
#pragma unroll
    for (int u = 0; u < kPerThread; ++u)
        o[u] = __builtin_nontemporal_load(&outputs4[base + 256 * u]);

#pragma unroll
    for (int u = 0; u < kPerThread; ++u) {
        const int i4 = base + 256 * u;
        f32x4 r;
#pragma unroll
        for (int j = 0; j < 4; ++j) {
            const float x = fminf(fmaxf(o[u][j], kClipLo), kClipHi);
            float rv = x;  // cold path: out = cosine
            if (i4 * 4 + j == hotIdx) {
                // hot: exactly one element per row
                rv = (x > kTH) ? clenshaw_phi(x, coeffs) : (x - kMM);
            }
            r[j] = kSCALE * rv;
        }
        __builtin_nontemporal_store(r, &dst4[i4]);
    }
}

}  // namespace

extern "C" void kernel_launch(void* const* d_in, const int* in_sizes, int n_in,
                              void* d_out, int out_size, void* d_ws, size_t ws_size,
                              hipStream_t stream) {
    const float* outputs = (const float*)d_in[0];
    const float* targets = (const float*)d_in[1];
    const float* coeffs  = (const float*)d_in[2];
    float* dst  = (float*)d_out;
    int* labels = (int*)d_ws;                     // 8192 ints = 32 KB

    const int n  = out_size;                      // 8192*8192
    const int n4 = n / 4;

    // k1: scan one-hot targets -> labels (L3-served, ~10us)
    scan_labels_kernel<<<2048, 256, 0, stream>>>(
        (const f32x4*)targets, labels, n4);

    // k2: 2-stream NT elementwise (16384 blocks, 4 float4/thread)
    const int perBlock = 256 * kPerThread;        // 1024 float4 / block
    const int grid = (n4 + perBlock - 1) / perBlock;
    cheb_aam_kernel<<<grid, 256, 0, stream>>>(
        (const f32x4*)outputs, labels, coeffs, (f32x4*)dst);
}